// Round 5
// baseline (2578.117 us; speedup 1.0000x reference)
//
#include <hip/hip_runtime.h>

// GRU recurrence, fused persistent kernel (round 5).
// Diagnosis r4: latency-serialized on ~88 L2 weight loads/lane/step with only
// 2 waves/SIMD; compiler (VGPR=128) sank my batched loads. This round:
//   (1) 1024-thread blocks: 16 waves, ONE 16-col tile per wave -> per-wave
//       serial vmem halves, 4 waves/SIMD overlap stalls.
//   (2) w_state staged into LDS once (128KB) -> phase 2 has zero vmem.
//   (3) x(t+1) prefetch kept; w_ih/w_hh streamed in independent 8-frag slices.

typedef __attribute__((ext_vector_type(8))) short short8;   // 8 x bf16 MFMA frag
typedef __attribute__((ext_vector_type(4))) float f32x4;
typedef __attribute__((ext_vector_type(2))) unsigned int uint2v;

constexpr int B_ = 1024, T_ = 128, I_ = 128, H_ = 256, OUT_ = 64;
constexpr int ROWS = 16;        // batch rows per block
constexpr int NBLK = B_ / ROWS; // 64 blocks

#define DEVI __device__ __forceinline__

DEVI unsigned short f2b(float f) {  // RNE float->bf16 (finite values only here)
    unsigned u = __builtin_bit_cast(unsigned, f);
    u += 0x7fffu + ((u >> 16) & 1u);
    return (unsigned short)(u >> 16);
}
DEVI float sigmoidf_(float x) { float e = __expf(-x); return __fdividef(1.f, 1.f + e); }
DEVI float tanhf_(float x) { float e = __expf(2.f * x); return __fdividef(e - 1.f, e + 1.f); }

DEVI short8 ldg8(const unsigned short* p) {   // 8 bf16 = one 16B load
    return __builtin_bit_cast(short8, *reinterpret_cast<const uint4*>(p));
}
DEVI short8 cvt8(const float* p) {            // 8 f32 -> bf16 fragment
    f32x4 lo = *reinterpret_cast<const f32x4*>(p);
    f32x4 hi = *reinterpret_cast<const f32x4*>(p + 4);
    union { unsigned short s[8]; short8 v; } r;
#pragma unroll
    for (int e = 0; e < 4; ++e) { r.s[e] = f2b(lo[e]); r.s[4 + e] = f2b(hi[e]); }
    return r.v;
}
DEVI f32x4 mfma(short8 a, short8 b, f32x4 c) {
    return __builtin_amdgcn_mfma_f32_16x16x32_bf16(a, b, c, 0, 0, 0);
}

// XOR-swizzled addressing into a [*][256] bf16 LDS tile (row-major, unpadded).
// byte ^= (row&7)<<4 : rows spread across bank-groups; 16B granularity preserved.
DEVI unsigned short* swz(unsigned short* base, int row, int col) {
    int byte = (row * H_ + col) * 2;
    byte ^= (row & 7) << 4;
    return (unsigned short*)((char*)base + byte);
}
DEVI const unsigned short* swzc(const unsigned short* base, int row, int col) {
    int byte = (row * H_ + col) * 2;
    byte ^= (row & 7) << 4;
    return (const unsigned short*)((const char*)base + byte);
}

// ---- weight pre-conversion: f32 -> bf16 into d_ws (n % 8 == 0) ----
__global__ void cvt_w(const float* __restrict__ src, unsigned short* __restrict__ dst, int n) {
    int i = (blockIdx.x * blockDim.x + threadIdx.x) * 8;
    if (i >= n) return;
    f32x4 lo = *reinterpret_cast<const f32x4*>(src + i);
    f32x4 hi = *reinterpret_cast<const f32x4*>(src + i + 4);
    union { unsigned short s[8]; uint4 v; } r;
#pragma unroll
    for (int e = 0; e < 4; ++e) { r.s[e] = f2b(lo[e]); r.s[4 + e] = f2b(hi[e]); }
    *reinterpret_cast<uint4*>(dst + i) = r.v;
}

__global__ __launch_bounds__(1024, 4) void gru_fused(
    const float* __restrict__ s0,             // [B][H] f32
    const float* __restrict__ a,              // [B][T][I] f32
    const unsigned short* __restrict__ w_ih,  // [3H][I] bf16 (ws)  rows: r,z,n
    const unsigned short* __restrict__ w_hh,  // [3H][H] bf16 (ws)
    const unsigned short* __restrict__ w_rw,  // [OUT][H] bf16 (ws)
    const unsigned short* __restrict__ w_st,  // [H][H] bf16 (ws)
    float* __restrict__ out_r,                // [T][OUT] f32
    float* __restrict__ out_s)                // [B][T][H] f32
{
    __shared__ unsigned short wst_l[H_ * H_];   // w_state, swizzled   131072 B
    __shared__ unsigned short h16[ROWS * H_];   // carry h bf16          8192 B
    __shared__ unsigned short hn16[ROWS * H_];  // h_new bf16            8192 B

    const int tid = threadIdx.x;
    const int w = tid >> 6;     // wave 0..15 -> one 16-col tile each
    const int l = tid & 63;
    const int m = l & 15;       // MFMA A row / B col within tile
    const int kg = l >> 4;      // k-group 0..3 (8 contiguous k each)
    const int R0 = blockIdx.x * ROWS;
    const int gcol = w * 16 + m;   // this wave's gate/state column

    // ---- stage w_state into LDS (once), swizzled; 8 x uint4 per thread ----
#pragma unroll
    for (int i = 0; i < 8; ++i) {
        const int idx = (tid + i * 1024) * 8;        // element index, 16B chunks
        const int row = idx >> 8, col = idx & 255;
        *reinterpret_cast<uint4*>(swz(wst_l, row, col)) =
            *reinterpret_cast<const uint4*>(w_st + idx);
    }

    // f32 carry in registers: hreg[v] = h[kg*4+v][gcol]
    // (phase-2 writer lane == phase-1 reader lane for each (row,col))
    float hreg[4];
#pragma unroll
    for (int v = 0; v < 4; ++v)
        hreg[v] = s0[(size_t)(R0 + kg * 4 + v) * H_ + gcol];

    // bf16 shadow of h: row w, cols l*4..l*4+3 (wave w covers row w)
    {
        const float* sp = &s0[(size_t)(R0 + w) * H_ + l * 4];
        f32x4 sv = *reinterpret_cast<const f32x4*>(sp);
        union { unsigned short s[4]; uint2v v; } pk;
#pragma unroll
        for (int e = 0; e < 4; ++e) pk.s[e] = f2b(sv[e]);
        *reinterpret_cast<uint2v*>(swz(h16, w, l * 4)) = pk.v;
    }
    __syncthreads();

    // x fragments for t=0
    short8 xa[4];
    {
        const float* xr = a + (size_t)(R0 + m) * T_ * I_ + kg * 8;
#pragma unroll
        for (int kt = 0; kt < 4; ++kt) xa[kt] = cvt8(xr + kt * 32);
    }

    for (int t = 0; t < T_; ++t) {
        // ---- phase 1: gate GEMM + in-register GRU elementwise -> hn16 ----
        short8 ha[8];
#pragma unroll
        for (int kt = 0; kt < 8; ++kt)
            ha[kt] = ldg8(swzc(h16, m, kt * 32 + kg * 8));

        f32x4 ar  = {0.f, 0.f, 0.f, 0.f};
        f32x4 az  = {0.f, 0.f, 0.f, 0.f};
        f32x4 ani = {0.f, 0.f, 0.f, 0.f};
        f32x4 anh = {0.f, 0.f, 0.f, 0.f};

        {   // x part, K=128, all three slices (36 fragment loads issued together)
            const unsigned short* pwi = w_ih + (size_t)gcol * I_ + kg * 8;
            short8 wi0[4], wi1[4], wi2[4];
#pragma unroll
            for (int kt = 0; kt < 4; ++kt) {
                wi0[kt] = ldg8(pwi + kt * 32);
                wi1[kt] = ldg8(pwi + 256 * I_ + kt * 32);
                wi2[kt] = ldg8(pwi + 512 * I_ + kt * 32);
            }
#pragma unroll
            for (int kt = 0; kt < 4; ++kt) {
                ar  = mfma(xa[kt], wi0[kt], ar);
                az  = mfma(xa[kt], wi1[kt], az);
                ani = mfma(xa[kt], wi2[kt], ani);
            }
        }
        {   // xa dead: prefetch x(t+1) — overlaps h-part MFMAs and phase 2
            const int tn = (t + 1 < T_) ? t + 1 : t;
            const float* xr = a + ((size_t)(R0 + m) * T_ + tn) * I_ + kg * 8;
#pragma unroll
            for (int kt = 0; kt < 4; ++kt) xa[kt] = cvt8(xr + kt * 32);
        }
        {   // h part, K=256, three independent 8-frag slices
            const unsigned short* pwh = w_hh + (size_t)gcol * H_ + kg * 8;
            short8 wb[8];
#pragma unroll
            for (int kt = 0; kt < 8; ++kt) wb[kt] = ldg8(pwh + kt * 32);
#pragma unroll
            for (int kt = 0; kt < 8; ++kt) ar = mfma(ha[kt], wb[kt], ar);
#pragma unroll
            for (int kt = 0; kt < 8; ++kt) wb[kt] = ldg8(pwh + 256 * H_ + kt * 32);
#pragma unroll
            for (int kt = 0; kt < 8; ++kt) az = mfma(ha[kt], wb[kt], az);
#pragma unroll
            for (int kt = 0; kt < 8; ++kt) wb[kt] = ldg8(pwh + 512 * H_ + kt * 32);
#pragma unroll
            for (int kt = 0; kt < 8; ++kt) anh = mfma(ha[kt], wb[kt], anh);
        }
        // D mapping: row = kg*4+v (batch), col = m -> this wave's gcol
#pragma unroll
        for (int v = 0; v < 4; ++v) {
            const float rg = sigmoidf_(ar[v]);
            const float zg = sigmoidf_(az[v]);
            const float ng = tanhf_(ani[v] + rg * anh[v]);
            *swz(hn16, kg * 4 + v, gcol) = f2b((1.f - zg) * ng + zg * hreg[v]);
        }
        __syncthreads();

        // ---- phase 2: s_next = sig(h_new @ w_state^T), all operands LDS ----
        short8 na[8];
#pragma unroll
        for (int kt = 0; kt < 8; ++kt)
            na[kt] = ldg8(swzc(hn16, m, kt * 32 + kg * 8));

        f32x4 acc = {0.f, 0.f, 0.f, 0.f};
#pragma unroll
        for (int kt = 0; kt < 8; ++kt)
            acc = mfma(na[kt], ldg8(swzc(wst_l, gcol, kt * 32 + kg * 8)), acc);
#pragma unroll
        for (int v = 0; v < 4; ++v) {
            const int row = kg * 4 + v;
            const float s = sigmoidf_(acc[v]);
            hreg[v] = s;                                        // f32 carry
            *swz(h16, row, gcol) = f2b(s);                      // bf16 shadow
            out_s[((size_t)(R0 + row) * T_ + t) * H_ + gcol] = s;
        }
        if (blockIdx.x == 0 && w < 4) {  // r_t = sig(h_new[0] @ w_reward^T)
            const int o = w * 16 + m;    // 0..63
            f32x4 accr = {0.f, 0.f, 0.f, 0.f};
            const unsigned short* p = w_rw + (size_t)o * H_ + kg * 8;
#pragma unroll
            for (int kt = 0; kt < 8; ++kt)
                accr = mfma(na[kt], ldg8(p + kt * 32), accr);
            if (kg == 0)  // batch row 0 = D row 0 = lanes 0..15, reg 0
                out_r[t * OUT_ + o] = sigmoidf_(accr[0]);
        }
        __syncthreads();
    }
}

extern "C" void kernel_launch(void* const* d_in, const int* in_sizes, int n_in,
                              void* d_out, int out_size, void* d_ws, size_t ws_size,
                              hipStream_t stream) {
    const float* s0  = (const float*)d_in[0];
    const float* a   = (const float*)d_in[1];
    const float* wih = (const float*)d_in[2];
    const float* whh = (const float*)d_in[3];
    const float* wrw = (const float*)d_in[4];
    const float* wst = (const float*)d_in[5];

    // bf16 weight copies in workspace
    unsigned short* ws16 = (unsigned short*)d_ws;
    unsigned short* wih16 = ws16;                 // 768*128  = 98304
    unsigned short* whh16 = wih16 + 98304;        // 768*256  = 196608
    unsigned short* wrw16 = whh16 + 196608;       // 64*256   = 16384
    unsigned short* wst16 = wrw16 + 16384;        // 256*256  = 65536

    cvt_w<<<98304  / (256 * 8), 256, 0, stream>>>(wih, wih16, 98304);
    cvt_w<<<196608 / (256 * 8), 256, 0, stream>>>(whh, whh16, 196608);
    cvt_w<<<16384  / (256 * 8), 256, 0, stream>>>(wrw, wrw16, 16384);
    cvt_w<<<65536  / (256 * 8), 256, 0, stream>>>(wst, wst16, 65536);

    float* out = (float*)d_out;
    gru_fused<<<NBLK, 1024, 0, stream>>>(s0, a, wih16, whh16, wrw16, wst16,
                                         out, out + (size_t)T_ * OUT_);
}